// Round 5
// baseline (31.314 us; speedup 1.0000x reference)
//
#include <hip/hip_runtime.h>
#include <hip/hip_fp16.h>

#define MM 16      // mixtures
#define DD 128     // visible dims
#define CC 50      // categories
#define BB 32768   // batch
#define NP 64      // d-pairs (DD/2)
#define CP 2500    // CC*CC combined categories

// ---------------------------------------------------------------------------
// prep_pairs: grid = 64 d01 x 4 quarters = 256 blocks x 256 threads.
// Phase 1 (wave-parallel, PROVEN pattern from rounds 2/3): wave wv computes
// softmax for rows rr = wv*8..wv*8+7 (rr -> dloc=rr>>4, m=rr&15) via lane<50
// loads + shfl_xor reduce; stores bf16 to LDS lp[2][50][16].
// Phase 2 (after ONE __syncthreads, pure map): each thread builds entries
// e in [q*625, q*625+625): ptab[d01][e][m] = lp[0][c0][m] + lp[1][c1][m],
// packed as 8 fp16-pairs (32 B coalesced store). Blocks write disjoint ranges.
// ---------------------------------------------------------------------------
__global__ __launch_bounds__(256) void prep_pairs(
    const float* __restrict__ cate,   // [M][D][C] f32
    unsigned int* __restrict__ ptab)  // [NP][CP][8] u32 (fp16 pairs)
{
    __shared__ unsigned short lp[2][CC][MM];   // bf16, 3200 B

    const int tid  = threadIdx.x;
    const int d01  = blockIdx.x >> 2;
    const int q    = blockIdx.x & 3;
    const int wv   = tid >> 6;       // 0..3
    const int lane = tid & 63;

    #pragma unroll
    for (int i = 0; i < 8; ++i) {
        int rr   = wv * 8 + i;       // 0..31
        int dloc = rr >> 4;
        int m    = rr & 15;
        const float* row = cate + (m * DD + 2 * d01 + dloc) * CC;
        float v = (lane < CC) ? row[lane] : -1e30f;

        float mx = v;
        #pragma unroll
        for (int off = 32; off; off >>= 1)
            mx = fmaxf(mx, __shfl_xor(mx, off, 64));
        float e = (lane < CC) ? __expf(v - mx) : 0.f;
        #pragma unroll
        for (int off = 32; off; off >>= 1)
            e += __shfl_xor(e, off, 64);
        float lse = mx + __logf(e);

        if (lane < CC) {
            unsigned int bits = __float_as_uint(v - lse);
            bits += 0x7fffu + ((bits >> 16) & 1u);   // RNE to bf16
            lp[dloc][lane][m] = (unsigned short)(bits >> 16);
        }
    }
    __syncthreads();

    const int e_end = q * 625 + 625;
    for (int e = q * 625 + tid; e < e_end; e += 256) {
        int c0 = e / 50;
        int c1 = e - c0 * 50;
        const uint4* r0 = (const uint4*)&lp[0][c0][0];   // 16 bf16 = 32 B
        const uint4* r1 = (const uint4*)&lp[1][c1][0];
        uint4 A0 = r0[0], A1 = r0[1];
        uint4 B0 = r1[0], B1 = r1[1];
        unsigned int Aw[8] = {A0.x, A0.y, A0.z, A0.w, A1.x, A1.y, A1.z, A1.w};
        unsigned int Bw[8] = {B0.x, B0.y, B0.z, B0.w, B1.x, B1.y, B1.z, B1.w};
        unsigned int P[8];
        #pragma unroll
        for (int w = 0; w < 8; ++w) {
            float lo = __uint_as_float(Aw[w] << 16)
                     + __uint_as_float(Bw[w] << 16);
            float hi = __uint_as_float(Aw[w] & 0xffff0000u)
                     + __uint_as_float(Bw[w] & 0xffff0000u);
            __half2 h = __floats2half2_rn(lo, hi);   // lo = m=2w, hi = m=2w+1
            __builtin_memcpy(&P[w], &h, 4);
        }
        uint4* dst = (uint4*)(ptab + (size_t)(d01 * CP + e) * 8);
        dst[0] = make_uint4(P[0], P[1], P[2], P[3]);
        dst[1] = make_uint4(P[4], P[5], P[6], P[7]);
    }
}

// ---------------------------------------------------------------------------
// gather_pairs: 4 lanes per batch row; lane l owns mixtures 4l..4l+3 (one
// uint2 = 4 fp16 per d01 gather). 64 gathers per row. logw recomputed
// per-thread from mw (uniform ~40 flops) -- no cross-kernel logw dependency.
// Block = 256 threads = 64 rows; grid = 512 blocks.
// ---------------------------------------------------------------------------
__global__ __launch_bounds__(256) void gather_pairs(
    const int* __restrict__ x,            // [B][D] int32
    const uint2* __restrict__ ptab,       // [NP][CP][4] uint2
    const float* __restrict__ mw,         // [M]
    float* __restrict__ out)              // [B]
{
    const int tid = threadIdx.x;
    const int l   = tid & 3;          // mixture-quad
    const int r   = tid >> 2;         // 0..63
    const int b   = blockIdx.x * 64 + r;

    // uniform log-softmax denominator of mixture weights
    float mmx = -1e30f;
    #pragma unroll
    for (int k = 0; k < MM; ++k) mmx = fmaxf(mmx, mw[k]);
    float s = 0.f;
    #pragma unroll
    for (int k = 0; k < MM; ++k) s += __expf(mw[k] - mmx);
    float lsew = mmx + __logf(s);

    const int4* __restrict__ xrow = (const int4*)(x + b * DD);

    float a0 = 0.f, a1 = 0.f, a2 = 0.f, a3 = 0.f;

    #pragma unroll 1
    for (int g = 0; g < 4; ++g) {
        #pragma unroll
        for (int j = 0; j < 8; ++j) {
            int jj = g * 8 + j;               // int4 index: x[4jj..4jj+3]
            int4 xv = xrow[jj];
            int ca = xv.x * CC + xv.y;        // pair d01 = 2jj
            int cb = xv.z * CC + xv.w;        // pair d01 = 2jj+1
            uint2 ua = ptab[((2 * jj)     * CP + ca) * 4 + l];
            uint2 ub = ptab[((2 * jj + 1) * CP + cb) * 4 + l];
            __half2 h; float2 f;
            __builtin_memcpy(&h, &ua.x, 4); f = __half22float2(h); a0 += f.x; a1 += f.y;
            __builtin_memcpy(&h, &ua.y, 4); f = __half22float2(h); a2 += f.x; a3 += f.y;
            __builtin_memcpy(&h, &ub.x, 4); f = __half22float2(h); a0 += f.x; a1 += f.y;
            __builtin_memcpy(&h, &ub.y, 4); f = __half22float2(h); a2 += f.x; a3 += f.y;
        }
    }

    float l0 = a0 + mw[4 * l + 0] - lsew;
    float l1 = a1 + mw[4 * l + 1] - lsew;
    float l2 = a2 + mw[4 * l + 2] - lsew;
    float l3 = a3 + mw[4 * l + 3] - lsew;

    float mx = fmaxf(fmaxf(l0, l1), fmaxf(l2, l3));
    mx = fmaxf(mx, __shfl_xor(mx, 1, 64));
    mx = fmaxf(mx, __shfl_xor(mx, 2, 64));
    float e = __expf(l0 - mx) + __expf(l1 - mx) + __expf(l2 - mx) + __expf(l3 - mx);
    e += __shfl_xor(e, 1, 64);
    e += __shfl_xor(e, 2, 64);

    if (l == 0) out[b] = mx + __logf(e);
}

extern "C" void kernel_launch(void* const* d_in, const int* in_sizes, int n_in,
                              void* d_out, int out_size, void* d_ws, size_t ws_size,
                              hipStream_t stream) {
    const int*   x    = (const int*)d_in[0];     // [B][D]
    const float* mw   = (const float*)d_in[1];   // [M]
    const float* cate = (const float*)d_in[2];   // [M][D][C]
    float* out = (float*)d_out;

    unsigned int* ptab = (unsigned int*)d_ws;    // NP*CP*16 fp16 = 5.12 MB

    prep_pairs<<<256, 256, 0, stream>>>(cate, ptab);
    gather_pairs<<<512, 256, 0, stream>>>(x, (const uint2*)ptab, mw, out);
}